// Round 6
// baseline (110.915 us; speedup 1.0000x reference)
//
#include <hip/hip_runtime.h>
#include <hip/hip_bf16.h>

// MoE token scatter: out[dest[t], :] = token_hidden[t, :] where
// dest[t] = expert_offsets[expert_idx[t]] + slot_idx[t]  (a bijection:
// rows == num_tokens, every output row written exactly once).
//
// Ladder: R1 scatter 1-row/256t = 101.2 us. R3 grid-stride+NT = 104.5 (rev).
// R4 4-row thread-batch = 105.8 (rev). R5 4-row/1024t scatter = 100.5
// (5.34 TB/s = 85% of m13's 6.29 TB/s copy ceiling).
//
// This round: invert the permutation. Pass 1 builds inv[dest]=t in d_ws
// (256 KB, ~2-3 us). Pass 2: block owns OUTPUT row -> perfectly sequential
// write stream, gathered 4 KB reads. Tests whether scattered dirty-line
// eviction (write-side HBM page locality) is the 15% gap vs the copy
// ceiling. Reads tolerate scatter (reorderable/prefetchable); writes don't.

#define HIDDEN 1024
#define VEC 4                     // floats per thread
#define SLICE (HIDDEN / VEC)      // 256 threads per row
#define RPB 4                     // rows per block
#define THREADS (SLICE * RPB)     // 1024

typedef float f32x4 __attribute__((ext_vector_type(4)));

__global__ void build_inv_kernel(
    const int* __restrict__ expert_idx,
    const int* __restrict__ slot_idx,
    const int* __restrict__ expert_offsets,
    int* __restrict__ inv,
    int num_tokens) {
    const int t = blockIdx.x * blockDim.x + threadIdx.x;
    if (t < num_tokens) {
        inv[expert_offsets[expert_idx[t]] + slot_idx[t]] = t;
    }
}

__global__ __launch_bounds__(THREADS) void moe_gather_kernel(
    const float* __restrict__ token_hidden,
    const int* __restrict__ inv,
    float* __restrict__ out) {
    const int slice = threadIdx.x >> 8;    // which output row of this block
    const int lane  = threadIdx.x & 255;   // float4 index within the row

    const int d = blockIdx.x * RPB + slice;  // output row (sequential)
    const int t = inv[d];                    // source token row (gathered)

    const f32x4* __restrict__ src =
        reinterpret_cast<const f32x4*>(token_hidden + (size_t)t * HIDDEN);
    f32x4* __restrict__ dst =
        reinterpret_cast<f32x4*>(out + (size_t)d * HIDDEN);

    dst[lane] = src[lane];
}

// Fallback (R5 structure) if d_ws is too small for the inverse map.
__global__ __launch_bounds__(THREADS) void moe_scatter_kernel(
    const float* __restrict__ token_hidden,
    const int* __restrict__ expert_idx,
    const int* __restrict__ slot_idx,
    const int* __restrict__ expert_offsets,
    float* __restrict__ out) {
    const int slice = threadIdx.x >> 8;
    const int lane  = threadIdx.x & 255;

    const int t    = blockIdx.x * RPB + slice;
    const int dest = expert_offsets[expert_idx[t]] + slot_idx[t];

    const f32x4* __restrict__ src =
        reinterpret_cast<const f32x4*>(token_hidden + (size_t)t * HIDDEN);
    f32x4* __restrict__ dst =
        reinterpret_cast<f32x4*>(out + (size_t)dest * HIDDEN);

    dst[lane] = src[lane];
}

extern "C" void kernel_launch(void* const* d_in, const int* in_sizes, int n_in,
                              void* d_out, int out_size, void* d_ws, size_t ws_size,
                              hipStream_t stream) {
    const float* token_hidden   = (const float*)d_in[0];
    const int*   expert_idx     = (const int*)d_in[1];
    const int*   slot_idx       = (const int*)d_in[2];
    const int*   expert_offsets = (const int*)d_in[3];
    float* out = (float*)d_out;

    const int num_tokens = in_sizes[1];  // expert_idx has one entry per token
    const int rows = out_size / HIDDEN;  // == num_tokens (bijection)

    if (ws_size >= (size_t)num_tokens * sizeof(int)) {
        int* inv = (int*)d_ws;
        build_inv_kernel<<<(num_tokens + 255) / 256, 256, 0, stream>>>(
            expert_idx, slot_idx, expert_offsets, inv, num_tokens);
        moe_gather_kernel<<<rows / RPB, THREADS, 0, stream>>>(
            token_hidden, inv, out);
    } else {
        moe_scatter_kernel<<<num_tokens / RPB, THREADS, 0, stream>>>(
            token_hidden, expert_idx, slot_idx, expert_offsets, out);
    }
}

// Round 7
// 99.212 us; speedup vs baseline: 1.1180x; 1.1180x over previous
//
#include <hip/hip_runtime.h>
#include <hip/hip_bf16.h>

// MoE token scatter: out[dest[t], :] = token_hidden[t, :] where
// dest[t] = expert_offsets[expert_idx[t]] + slot_idx[t]  (a bijection:
// rows == num_tokens, every output row written exactly once -> no zero-init).
//
// FINAL (best) structure = R5: 4 rows per 1024-thread block, each 256-thread
// slice moves one row as 256 float4s; 1 load + 1 store per thread, nothing
// else. 100.5 us = 5.34 TB/s effective (537 MB), 85% of m13's 6.29 TB/s
// sequential-copy ceiling.
//
// Isolated and rejected:
//   R3 grid-stride + nontemporal: 104.5 us (-4%)
//   R4 4-rows-per-thread batching: 105.8 us (-5%)
//   R5 4x fewer dispatches: 100.5 (dispatch overhead not a limiter)
//   R6 inverse map + sequential-write gather: 110.9 us (-10%) -> write-side
//      scatter is NOT the gap; permuted 4 KB rows at ~85% of the sequential
//      copy ceiling is the HBM floor for this access pattern.

#define HIDDEN 1024
#define VEC 4                     // floats per thread
#define SLICE (HIDDEN / VEC)      // 256 threads per row
#define RPB 4                     // rows per block
#define THREADS (SLICE * RPB)     // 1024

typedef float f32x4 __attribute__((ext_vector_type(4)));

__global__ __launch_bounds__(THREADS) void moe_scatter_kernel(
    const float* __restrict__ token_hidden,
    const int* __restrict__ expert_idx,
    const int* __restrict__ slot_idx,
    const int* __restrict__ expert_offsets,
    float* __restrict__ out) {
    const int slice = threadIdx.x >> 8;    // which row of this block (0..3)
    const int lane  = threadIdx.x & 255;   // float4 index within the row

    const int t    = blockIdx.x * RPB + slice;
    const int dest = expert_offsets[expert_idx[t]] + slot_idx[t];

    const f32x4* __restrict__ src =
        reinterpret_cast<const f32x4*>(token_hidden + (size_t)t * HIDDEN);
    f32x4* __restrict__ dst =
        reinterpret_cast<f32x4*>(out + (size_t)dest * HIDDEN);

    dst[lane] = src[lane];
}

extern "C" void kernel_launch(void* const* d_in, const int* in_sizes, int n_in,
                              void* d_out, int out_size, void* d_ws, size_t ws_size,
                              hipStream_t stream) {
    const float* token_hidden   = (const float*)d_in[0];
    const int*   expert_idx     = (const int*)d_in[1];
    const int*   slot_idx       = (const int*)d_in[2];
    const int*   expert_offsets = (const int*)d_in[3];
    float* out = (float*)d_out;

    const int num_tokens = in_sizes[1];  // expert_idx has one entry per token

    moe_scatter_kernel<<<num_tokens / RPB, THREADS, 0, stream>>>(
        token_hidden, expert_idx, slot_idx, expert_offsets, out);
}